// Round 4
// baseline (18673.819 us; speedup 1.0000x reference)
//
#include <hip/hip_runtime.h>
#include <hip/hip_bf16.h>

// B=64, S=2048, WIN=50, E=128, H=256, G=4H=1024.
#define B_ 64
#define S_ 2048
#define W_ 50
#define E_ 128
#define H_ 256
#define G_ 1024

typedef unsigned short u16;

// Module-global scratch (BSS; d_ws is untrusted/unknown size).
__device__ int g_mode;                          // 0 = buffers are bf16, 1 = buffers are fp32
__device__ u16 g_WihT[E_ * G_];                 // [e][4u+q] = Wih[q*H+u][e]  (bf16 canonical)
__device__ u16 g_WhhT[H_ * G_];                 // [k][4u+q] = Whh[q*H+u][k]  (bf16 canonical)
__device__ u16 g_xg[(size_t)B_ * S_ * G_];      // 256 MB x-gates incl. biases (bf16 canonical)

__device__ __forceinline__ float b2f(u16 u) {
    union { unsigned int i; float f; } v;
    v.i = ((unsigned int)u) << 16;
    return v.f;
}
__device__ __forceinline__ u16 f2b(float f) {
    __hip_bfloat16 h = __float2bfloat16(f);
    return *reinterpret_cast<u16*>(&h);
}
// mode-aware input load: element i of a harness input buffer
__device__ __forceinline__ float ldin(int mode, const void* p, size_t i) {
    return mode ? ((const float*)p)[i] : b2f(((const u16*)p)[i]);
}
__device__ __forceinline__ float clamp30(float x) {
    return fminf(fmaxf(x, -30.0f), 30.0f);      // transparent for |x|<30; also squashes NaN
}
__device__ __forceinline__ float sigmoidf_(float x) { return 1.0f / (1.0f + __expf(-x)); }
__device__ __forceinline__ float tanhf_(float x) {
    float e = __expf(2.0f * x);
    return 1.0f - 2.0f / (e + 1.0f);
}

// ---------- K0: dtype sniffer ----------
// bf16 data: every u16 is a real bf16 of ~0.1*N(0,1) -> exponent in [96,143] (or 0). ~100% sane.
// fp32 data: odd u16s sane (high halves), even u16s uniform bits -> ~19% sane. Total ~60%.
__global__ void sniff_kernel(const u16* __restrict__ wemb) {
    int sane = 0;
    for (int i = 0; i < 2048; ++i) {
        int ex = (wemb[i] >> 7) & 0xFF;
        if (ex == 0 || (ex >= 96 && ex <= 143)) ++sane;
    }
    g_mode = (sane >= 1900) ? 0 : 1;
}

// ---------- gate-interleaved transposes (mode-aware source) ----------
__global__ __launch_bounds__(256) void transpose_whh(const void* __restrict__ src) {
    const int mode = g_mode;
    int i = blockIdx.x * 256 + threadIdx.x;          // i = k*G + 4u+q, i < H*G
    int k = i >> 10, r = i & 1023, u = r >> 2, q = r & 3;
    g_WhhT[i] = f2b(ldin(mode, src, (size_t)((q << 16) + (u << 8) + k)));
}
__global__ __launch_bounds__(256) void transpose_wih(const void* __restrict__ src) {
    const int mode = g_mode;
    int i = blockIdx.x * 256 + threadIdx.x;          // i = e*G + 4u+q, i < E*G
    int e = i >> 10, r = i & 1023, u = r >> 2, q = r & 3;
    g_WihT[i] = f2b(ldin(mode, src, (size_t)((q << 15) + (u << 7) + e)));
}

// ---------- K1: fused embedding + input projection ----------
__global__ __launch_bounds__(256) void xg_kernel(const void* __restrict__ pw,
                                                 const void* __restrict__ Wemb,
                                                 const void* __restrict__ bemb,
                                                 const void* __restrict__ bih,
                                                 const void* __restrict__ bhh) {
    const int mode = g_mode;
    const int t = threadIdx.x;
    const int m0 = blockIdx.x * 16;
    __shared__ float pw16[16][W_ + 2];
    __shared__ float Wl[E_ * 51];
    __shared__ __align__(16) float erow[16][E_];

    for (int i = t; i < E_ * W_; i += 256) {
        int e = i / W_, w = i - e * W_;
        Wl[e * 51 + w] = ldin(mode, Wemb, i);
    }
    for (int i = t; i < 16 * W_; i += 256) {
        int r = i / W_, w = i - r * W_;
        pw16[r][w] = ldin(mode, pw, (size_t)(m0 + r) * W_ + w);
    }
    __syncthreads();

#pragma unroll
    for (int i = 0; i < 8; ++i) {
        int idx = i * 256 + t;
        int r = idx >> 7, e = idx & 127;
        float a = ldin(mode, bemb, e);
        const float* wr = &Wl[e * 51];
#pragma unroll
        for (int w = 0; w < W_; ++w) a = fmaf(pw16[r][w], wr[w], a);
        erow[r][e] = fmaxf(a, 0.0f);                 // relu (also squashes NaN)
    }
    __syncthreads();

    const int g0 = 4 * t;
    float acc[16][4];
    {
        float b0 = ldin(mode, bih, t) + ldin(mode, bhh, t);
        float b1 = ldin(mode, bih, H_ + t) + ldin(mode, bhh, H_ + t);
        float b2 = ldin(mode, bih, 2 * H_ + t) + ldin(mode, bhh, 2 * H_ + t);
        float b3 = ldin(mode, bih, 3 * H_ + t) + ldin(mode, bhh, 3 * H_ + t);
#pragma unroll
        for (int r = 0; r < 16; ++r) { acc[r][0] = b0; acc[r][1] = b1; acc[r][2] = b2; acc[r][3] = b3; }
    }
    for (int e = 0; e < E_; e += 4) {
        ushort4 w0 = *(const ushort4*)(g_WihT + (size_t)(e + 0) * G_ + g0);
        ushort4 w1 = *(const ushort4*)(g_WihT + (size_t)(e + 1) * G_ + g0);
        ushort4 w2 = *(const ushort4*)(g_WihT + (size_t)(e + 2) * G_ + g0);
        ushort4 w3 = *(const ushort4*)(g_WihT + (size_t)(e + 3) * G_ + g0);
        float f00 = b2f(w0.x), f01 = b2f(w0.y), f02 = b2f(w0.z), f03 = b2f(w0.w);
        float f10 = b2f(w1.x), f11 = b2f(w1.y), f12 = b2f(w1.z), f13 = b2f(w1.w);
        float f20 = b2f(w2.x), f21 = b2f(w2.y), f22 = b2f(w2.z), f23 = b2f(w2.w);
        float f30 = b2f(w3.x), f31 = b2f(w3.y), f32 = b2f(w3.z), f33 = b2f(w3.w);
#pragma unroll
        for (int r = 0; r < 16; ++r) {
            float4 ev = *(const float4*)&erow[r][e];
            acc[r][0] = fmaf(ev.x, f00, acc[r][0]); acc[r][1] = fmaf(ev.x, f01, acc[r][1]);
            acc[r][2] = fmaf(ev.x, f02, acc[r][2]); acc[r][3] = fmaf(ev.x, f03, acc[r][3]);
            acc[r][0] = fmaf(ev.y, f10, acc[r][0]); acc[r][1] = fmaf(ev.y, f11, acc[r][1]);
            acc[r][2] = fmaf(ev.y, f12, acc[r][2]); acc[r][3] = fmaf(ev.y, f13, acc[r][3]);
            acc[r][0] = fmaf(ev.z, f20, acc[r][0]); acc[r][1] = fmaf(ev.z, f21, acc[r][1]);
            acc[r][2] = fmaf(ev.z, f22, acc[r][2]); acc[r][3] = fmaf(ev.z, f23, acc[r][3]);
            acc[r][0] = fmaf(ev.w, f30, acc[r][0]); acc[r][1] = fmaf(ev.w, f31, acc[r][1]);
            acc[r][2] = fmaf(ev.w, f32, acc[r][2]); acc[r][3] = fmaf(ev.w, f33, acc[r][3]);
        }
    }
#pragma unroll
    for (int r = 0; r < 16; ++r) {
        ushort4 sv;
        sv.x = f2b(acc[r][0]); sv.y = f2b(acc[r][1]);
        sv.z = f2b(acc[r][2]); sv.w = f2b(acc[r][3]);
        *(ushort4*)(g_xg + (size_t)(m0 + r) * G_ + g0) = sv;
    }
}

// ---------- K2: recurrence + output head ----------
__global__ __launch_bounds__(256) void lstm_kernel(const void* __restrict__ Wout,
                                                   const void* __restrict__ bout,
                                                   const void* __restrict__ h0,
                                                   const void* __restrict__ c0,
                                                   void* __restrict__ yv) {
    const int mode = g_mode;
    const int t = threadIdx.x;
    const int b = blockIdx.x;
    __shared__ __align__(16) float h_lds[H_];
    __shared__ float red[4];

    float c = ldin(mode, c0, b * H_ + t);
    h_lds[t] = ldin(mode, h0, b * H_ + t);
    const float wo = ldin(mode, Wout, t);
    const float bo = ldin(mode, bout, 0);
    const u16* xp = g_xg + (size_t)b * S_ * G_ + 4 * t;
    const u16* __restrict__ wh = g_WhhT + 4 * t;
    __syncthreads();

    for (int s = 0; s < S_; ++s) {
        ushort4 xv = *(const ushort4*)xp;            // biases already folded in
        float ai = 0.f, af = 0.f, ag = 0.f, ao = 0.f;
#pragma unroll 8
        for (int k = 0; k < H_; k += 4) {
            float4 h4 = *(const float4*)(h_lds + k);
            ushort4 wa = *(const ushort4*)(wh + (size_t)(k + 0) * G_);
            ushort4 wb = *(const ushort4*)(wh + (size_t)(k + 1) * G_);
            ushort4 wc = *(const ushort4*)(wh + (size_t)(k + 2) * G_);
            ushort4 wd = *(const ushort4*)(wh + (size_t)(k + 3) * G_);
            ai = fmaf(h4.x, b2f(wa.x), ai); af = fmaf(h4.x, b2f(wa.y), af);
            ag = fmaf(h4.x, b2f(wa.z), ag); ao = fmaf(h4.x, b2f(wa.w), ao);
            ai = fmaf(h4.y, b2f(wb.x), ai); af = fmaf(h4.y, b2f(wb.y), af);
            ag = fmaf(h4.y, b2f(wb.z), ag); ao = fmaf(h4.y, b2f(wb.w), ao);
            ai = fmaf(h4.z, b2f(wc.x), ai); af = fmaf(h4.z, b2f(wc.y), af);
            ag = fmaf(h4.z, b2f(wc.z), ag); ao = fmaf(h4.z, b2f(wc.w), ao);
            ai = fmaf(h4.w, b2f(wd.x), ai); af = fmaf(h4.w, b2f(wd.y), af);
            ag = fmaf(h4.w, b2f(wd.z), ag); ao = fmaf(h4.w, b2f(wd.w), ao);
        }
        ai = clamp30(ai + b2f(xv.x)); af = clamp30(af + b2f(xv.y));
        ag = clamp30(ag + b2f(xv.z)); ao = clamp30(ao + b2f(xv.w));

        float ii = sigmoidf_(ai);
        float ff = sigmoidf_(af);
        float gv = tanhf_(ag);
        float oo = sigmoidf_(ao);
        c = fmaf(ff, c, ii * gv);
        float h = oo * tanhf_(c);

        __syncthreads();                             // (A) all h_lds reads for step s done
        h_lds[t] = h;
        float p = h * wo;
#pragma unroll
        for (int off = 32; off > 0; off >>= 1) p += __shfl_down(p, off, 64);
        if ((t & 63) == 0) red[t >> 6] = p;
        __syncthreads();                             // (B) h_lds + red ready
        if (t == 0) {
            float yv_f = sigmoidf_(clamp30(red[0] + red[1] + red[2] + red[3] + bo));
            if (mode) ((float*)yv)[(size_t)s * B_ + b] = yv_f;
            else      ((u16*)yv)[(size_t)s * B_ + b] = f2b(yv_f);
        }
        xp += G_;
    }
}

extern "C" void kernel_launch(void* const* d_in, const int* in_sizes, int n_in,
                              void* d_out, int out_size, void* d_ws, size_t ws_size,
                              hipStream_t stream) {
    const void* pw   = d_in[0];   // [B,S,50]
    const void* Wemb = d_in[1];   // [E,50]
    const void* bemb = d_in[2];   // [E]
    const void* Wih  = d_in[3];   // [G,E]
    const void* Whh  = d_in[4];   // [G,H]
    const void* bih  = d_in[5];   // [G]
    const void* bhh  = d_in[6];   // [G]
    const void* Wout = d_in[7];   // [1,H]
    const void* bout = d_in[8];   // [1]
    const void* h0   = d_in[9];   // [B,H]
    const void* c0   = d_in[10];  // [B,H]
    (void)d_ws; (void)ws_size;    // scratch lives in __device__ globals

    sniff_kernel<<<1, 1, 0, stream>>>((const u16*)Wemb);
    transpose_wih<<<(E_ * G_) / 256, 256, 0, stream>>>(Wih);
    transpose_whh<<<(H_ * G_) / 256, 256, 0, stream>>>(Whh);
    xg_kernel<<<(B_ * S_) / 16, 256, 0, stream>>>(pw, Wemb, bemb, bih, bhh);
    lstm_kernel<<<B_, 256, 0, stream>>>(Wout, bout, h0, c0, d_out);
}